// Round 1
// baseline (982.027 us; speedup 1.0000x reference)
//
#include <hip/hip_runtime.h>
#include <hip/hip_bf16.h>
#include <math.h>

#define DM    2048
#define DQKV  6144
#define NH    16
#define DH    128
#define TT    1024
#define BB    4

typedef __bf16 bf16_t;
typedef __bf16 bf16x8 __attribute__((ext_vector_type(8)));
typedef float  f32x4  __attribute__((ext_vector_type(4)));

// ---------------------------------------------------------------------------
// GEMM: C[M,N] = A[M,K](f32) @ W[K,N](f32) + bias[N], out bf16 or f32.
// 128x128 block tile, 256 threads (4 waves, 2x2), each wave 64x64 via 4x4
// grid of 16x16x32 bf16 MFMAs. fp32->bf16 cast fused into LDS staging.
// ---------------------------------------------------------------------------
template <bool OUT_BF16>
__global__ __launch_bounds__(256) void gemm_bias_kernel(
    const float* __restrict__ A, const float* __restrict__ W,
    const float* __restrict__ bias, void* __restrict__ out,
    int M, int N, int K) {
  // pad rows to 40 bf16 (80 B): keeps ds_read_b128 16B-aligned, <=2-way bank alias
  __shared__ __align__(16) bf16_t As[128][40];
  __shared__ __align__(16) bf16_t Bs[128][40];  // B stored transposed: Bs[n][k]

  const int tid  = threadIdx.x;
  const int lane = tid & 63;
  const int wave = tid >> 6;
  const int ln   = lane & 15;
  const int quad = lane >> 4;
  const int bm = blockIdx.y, bn = blockIdx.x;
  const int m0 = (wave >> 1) * 64;
  const int n0 = (wave & 1) * 64;

  f32x4 acc[4][4] = {};

  const int kTiles = K >> 5;
  for (int kt = 0; kt < kTiles; ++kt) {
    __syncthreads();
    // stage A-tile: 128 rows x 32 cols fp32 -> bf16
#pragma unroll
    for (int i = 0; i < 4; ++i) {
      int v = tid + i * 256;
      int row = v >> 3, cv = v & 7;
      const float4 a =
          *(const float4*)(A + (size_t)(bm * 128 + row) * K + kt * 32 + cv * 4);
      bf16_t* dst = &As[row][cv * 4];
      dst[0] = (bf16_t)a.x; dst[1] = (bf16_t)a.y;
      dst[2] = (bf16_t)a.z; dst[3] = (bf16_t)a.w;
    }
    // stage B-tile transposed: rows k 0..31, cols n 0..127
#pragma unroll
    for (int i = 0; i < 4; ++i) {
      int v = tid + i * 256;
      int k = v >> 5, cv = v & 31;
      const float4 w4 =
          *(const float4*)(W + (size_t)(kt * 32 + k) * N + bn * 128 + cv * 4);
      Bs[cv * 4 + 0][k] = (bf16_t)w4.x;
      Bs[cv * 4 + 1][k] = (bf16_t)w4.y;
      Bs[cv * 4 + 2][k] = (bf16_t)w4.z;
      Bs[cv * 4 + 3][k] = (bf16_t)w4.w;
    }
    __syncthreads();

    bf16x8 af[4], bfr[4];
#pragma unroll
    for (int i = 0; i < 4; ++i)
      af[i] = *(const bf16x8*)&As[m0 + 16 * i + ln][quad * 8];
#pragma unroll
    for (int j = 0; j < 4; ++j)
      bfr[j] = *(const bf16x8*)&Bs[n0 + 16 * j + ln][quad * 8];
#pragma unroll
    for (int i = 0; i < 4; ++i)
#pragma unroll
      for (int j = 0; j < 4; ++j)
        acc[i][j] = __builtin_amdgcn_mfma_f32_16x16x32_bf16(af[i], bfr[j],
                                                            acc[i][j], 0, 0, 0);
  }

  // epilogue: C/D layout col=lane&15, row=quad*4+reg  [measured m89/m91]
#pragma unroll
  for (int i = 0; i < 4; ++i) {
    int rowg = bm * 128 + m0 + 16 * i + quad * 4;
#pragma unroll
    for (int j = 0; j < 4; ++j) {
      int colg = bn * 128 + n0 + 16 * j + ln;
      float bb = bias[colg];
#pragma unroll
      for (int r = 0; r < 4; ++r) {
        float val = acc[i][j][r] + bb;
        if (OUT_BF16)
          ((bf16_t*)out)[(size_t)(rowg + r) * N + colg] = (bf16_t)val;
        else
          ((float*)out)[(size_t)(rowg + r) * N + colg] = val;
      }
    }
  }
}

// ---------------------------------------------------------------------------
// Flash attention, causal. Block = (b, h, 64-row q-tile), 256 threads.
// Wave w owns q rows [qt*64 + w*16, +16). K-chunks of 64 staged in LDS.
// qkv layout: [B*T][6144] bf16, Q at col h*128, K at 2048+h*128, V at 4096+h*128.
// attout: [B*T][2048] fp32, col h*128+d.
// ---------------------------------------------------------------------------
__global__ __launch_bounds__(256) void attn_kernel(
    const bf16_t* __restrict__ qkv, float* __restrict__ attout) {
  const int bx = blockIdx.x;
  const int qt = bx & 15;
  const int h  = (bx >> 4) & 15;
  const int b  = bx >> 8;
  const int tid  = threadIdx.x;
  const int lane = tid & 63;
  const int wave = tid >> 6;
  const int ln   = lane & 15;
  const int quad = lane >> 4;

  __shared__ __align__(16) bf16_t Ks[64][128];      // 16 KB
  __shared__ __align__(16) bf16_t Vt[128][64];      // 16 KB  Vt[d][kk]
  __shared__ __align__(16) bf16_t Ps[4][16][64];    //  8 KB  per-wave P

  const int q0 = qt * 64 + wave * 16;

  // Q fragments: A-layout m=ln, k=quad*8+j  (Dh=128 -> 4 frags)
  bf16x8 aq[4];
  {
    const bf16_t* qrow = qkv + (size_t)(b * TT + q0 + ln) * DQKV + h * DH;
#pragma unroll
    for (int kt = 0; kt < 4; ++kt)
      aq[kt] = *(const bf16x8*)(qrow + kt * 32 + quad * 8);
  }

  f32x4 o[8] = {};
  float mrow[4], lrow[4];
#pragma unroll
  for (int r = 0; r < 4; ++r) { mrow[r] = -1e30f; lrow[r] = 0.f; }

  const float scale = 0.08838834764831845f;  // 1/sqrt(128)
  const int nChunks = qt + 1;

  for (int c = 0; c < nChunks; ++c) {
    const int kc = c * 64;
    __syncthreads();  // protect Ks/Vt reuse
    // stage K chunk (row-major) and V chunk (transposed)
#pragma unroll
    for (int i = 0; i < 4; ++i) {
      int v = tid + i * 256;
      int kk = v >> 4, dv = v & 15;
      const bf16_t* krow = qkv + (size_t)(b * TT + kc + kk) * DQKV + DM + h * DH;
      *(bf16x8*)&Ks[kk][dv * 8] = *(const bf16x8*)(krow + dv * 8);
      bf16x8 vv = *(const bf16x8*)(krow + DM + dv * 8);  // V = K col + 2048
#pragma unroll
      for (int e = 0; e < 8; ++e) Vt[dv * 8 + e][kk] = vv[e];
    }
    __syncthreads();

    // S = Q K^T : 4 col-tiles x 4 K-steps
    f32x4 sacc[4];
#pragma unroll
    for (int jt = 0; jt < 4; ++jt) {
      sacc[jt] = (f32x4){0.f, 0.f, 0.f, 0.f};
#pragma unroll
      for (int kt = 0; kt < 4; ++kt) {
        bf16x8 bk = *(const bf16x8*)&Ks[jt * 16 + ln][kt * 32 + quad * 8];
        sacc[jt] =
            __builtin_amdgcn_mfma_f32_16x16x32_bf16(aq[kt], bk, sacc[jt], 0, 0, 0);
      }
    }

    // scale + causal mask + row max (rows live in quad, cols in ln)
    float s[4][4], mc[4];
#pragma unroll
    for (int r = 0; r < 4; ++r) mc[r] = -1e30f;
#pragma unroll
    for (int jt = 0; jt < 4; ++jt) {
      int colg = kc + jt * 16 + ln;
#pragma unroll
      for (int r = 0; r < 4; ++r) {
        int rowg = q0 + quad * 4 + r;
        float sv = sacc[jt][r] * scale;
        sv = (colg <= rowg) ? sv : -1e30f;
        s[jt][r] = sv;
        mc[r] = fmaxf(mc[r], sv);
      }
    }
#pragma unroll
    for (int off = 1; off < 16; off <<= 1)
#pragma unroll
      for (int r = 0; r < 4; ++r)
        mc[r] = fmaxf(mc[r], __shfl_xor(mc[r], off, 64));

    float alpha[4];
#pragma unroll
    for (int r = 0; r < 4; ++r) {
      float mnew = fmaxf(mrow[r], mc[r]);
      alpha[r] = __expf(mrow[r] - mnew);
      mrow[r] = mnew;
    }

    // P = exp(s - m), row sums, stage P to LDS in A-layout-readable form
    float rs[4] = {0.f, 0.f, 0.f, 0.f};
#pragma unroll
    for (int jt = 0; jt < 4; ++jt)
#pragma unroll
      for (int r = 0; r < 4; ++r) {
        float p = __expf(s[jt][r] - mrow[r]);
        rs[r] += p;
        Ps[wave][quad * 4 + r][jt * 16 + ln] = (bf16_t)p;
      }
#pragma unroll
    for (int off = 1; off < 16; off <<= 1)
#pragma unroll
      for (int r = 0; r < 4; ++r) rs[r] += __shfl_xor(rs[r], off, 64);
#pragma unroll
    for (int r = 0; r < 4; ++r) lrow[r] = lrow[r] * alpha[r] + rs[r];

    // rescale O
#pragma unroll
    for (int nt = 0; nt < 8; ++nt)
#pragma unroll
      for (int r = 0; r < 4; ++r) o[nt][r] *= alpha[r];

    __syncthreads();  // Ps cross-lane visibility (all waves same trip count)

    // O += P V : 2 K-steps of 32 x 8 d-tiles
#pragma unroll
    for (int ks = 0; ks < 2; ++ks) {
      bf16x8 ap = *(const bf16x8*)&Ps[wave][ln][ks * 32 + quad * 8];
#pragma unroll
      for (int nt = 0; nt < 8; ++nt) {
        bf16x8 bv = *(const bf16x8*)&Vt[nt * 16 + ln][ks * 32 + quad * 8];
        o[nt] = __builtin_amdgcn_mfma_f32_16x16x32_bf16(ap, bv, o[nt], 0, 0, 0);
      }
    }
  }

  // epilogue: normalize by l, write fp32 [B*T][2048]
#pragma unroll
  for (int r = 0; r < 4; ++r) {
    float inv = 1.0f / lrow[r];
    int t = q0 + quad * 4 + r;
    float* orow = attout + (size_t)(b * TT + t) * DM + h * DH;
#pragma unroll
    for (int nt = 0; nt < 8; ++nt) orow[nt * 16 + ln] = o[nt][r] * inv;
  }
}

// ---------------------------------------------------------------------------
extern "C" void kernel_launch(void* const* d_in, const int* in_sizes, int n_in,
                              void* d_out, int out_size, void* d_ws,
                              size_t ws_size, hipStream_t stream) {
  const float* x     = (const float*)d_in[0];
  const float* w_qkv = (const float*)d_in[1];
  const float* b_qkv = (const float*)d_in[2];
  const float* w_out = (const float*)d_in[3];
  const float* b_out = (const float*)d_in[4];
  float* out = (float*)d_out;

  // ws: qkv bf16 [4096][6144] (50.3 MB) | attout fp32 [4096][2048] (33.6 MB)
  bf16_t* qkv   = (bf16_t*)d_ws;
  float* attout = (float*)((char*)d_ws + (size_t)4096 * 6144 * 2);

  dim3 blk(256);
  gemm_bias_kernel<true>
      <<<dim3(48, 32), blk, 0, stream>>>(x, w_qkv, b_qkv, qkv, 4096, 6144, 2048);
  attn_kernel<<<dim3(1024), blk, 0, stream>>>(qkv, attout);
  gemm_bias_kernel<false>
      <<<dim3(16, 32), blk, 0, stream>>>(attout, w_out, b_out, out, 4096, 2048, 2048);
}

// Round 2
// 537.800 us; speedup vs baseline: 1.8260x; 1.8260x over previous
//
#include <hip/hip_runtime.h>
#include <hip/hip_bf16.h>
#include <math.h>

#define DM    2048
#define DQKV  6144
#define NH    16
#define DH    128
#define TT    1024
#define BB    4

typedef __bf16 bf16_t;
typedef __bf16 bf16x4 __attribute__((ext_vector_type(4)));
typedef __bf16 bf16x8 __attribute__((ext_vector_type(8)));
typedef float  f32x4  __attribute__((ext_vector_type(4)));

__device__ __forceinline__ void async16(const void* g, void* lds) {
  __builtin_amdgcn_global_load_lds(
      (const __attribute__((address_space(1))) unsigned int*)g,
      (__attribute__((address_space(3))) unsigned int*)lds, 16, 0, 0);
}

// ---------------------------------------------------------------------------
// cast fp32 -> bf16, 8 elems/thread
// ---------------------------------------------------------------------------
__global__ __launch_bounds__(256) void cast_kernel(const float* __restrict__ X,
                                                   bf16_t* __restrict__ Xb) {
  const size_t i = ((size_t)blockIdx.x * 256 + threadIdx.x) * 8;
  float4 a = *(const float4*)(X + i);
  float4 b = *(const float4*)(X + i + 4);
  bf16x8 o = {(bf16_t)a.x, (bf16_t)a.y, (bf16_t)a.z, (bf16_t)a.w,
              (bf16_t)b.x, (bf16_t)b.y, (bf16_t)b.z, (bf16_t)b.w};
  *(bf16x8*)(Xb + i) = o;
}

// ---------------------------------------------------------------------------
// W[K][N] fp32 -> Wt[N][K] bf16, 64x64 tiles
// ---------------------------------------------------------------------------
__global__ __launch_bounds__(256) void transpose_cast_kernel(
    const float* __restrict__ W, bf16_t* __restrict__ Wt, int K, int N) {
  __shared__ bf16_t tile[64][72];  // [k][n], padded
  const int tid = threadIdx.x;
  const int tk = blockIdx.y * 64, tn = blockIdx.x * 64;
  {
    int r = tid >> 2, c0 = (tid & 3) * 16;
    const float* src = W + (size_t)(tk + r) * N + tn + c0;
#pragma unroll
    for (int j = 0; j < 4; ++j) {
      float4 v = *(const float4*)(src + j * 4);
      tile[r][c0 + j * 4 + 0] = (bf16_t)v.x;
      tile[r][c0 + j * 4 + 1] = (bf16_t)v.y;
      tile[r][c0 + j * 4 + 2] = (bf16_t)v.z;
      tile[r][c0 + j * 4 + 3] = (bf16_t)v.w;
    }
  }
  __syncthreads();
  {
    int n = tid >> 2, c0 = (tid & 3) * 16;
    bf16_t* dst = Wt + (size_t)(tn + n) * K + tk + c0;
#pragma unroll
    for (int j = 0; j < 4; ++j) {
      bf16x4 t = {tile[c0 + j * 4 + 0][n], tile[c0 + j * 4 + 1][n],
                  tile[c0 + j * 4 + 2][n], tile[c0 + j * 4 + 3][n]};
      *(bf16x4*)(dst + j * 4) = t;
    }
  }
}

// ---------------------------------------------------------------------------
// GEMM: C[M,N] = A[M,K] @ Bt[N,K]^T + bias[N].  All bf16 inputs, fp32 acc.
// m97 structure: 128x128 tile, BK=64, global_load_lds width-16 staging with
// XOR chunk swizzle (LDS chunk (row,c) holds global chunk c^(row&7)) so the
// unpadded layout reads conflict-free. 4 waves, each 64x64 via 4x4 MFMA.
// ---------------------------------------------------------------------------
template <bool OUT_BF16>
__global__ __launch_bounds__(256) void gemm_bt_kernel(
    const bf16_t* __restrict__ A, const bf16_t* __restrict__ Bt,
    const float* __restrict__ bias, void* __restrict__ out,
    int M, int N, int K) {
  __shared__ __align__(16) bf16_t As[128 * 64];
  __shared__ __align__(16) bf16_t Bs[128 * 64];

  const int tid  = threadIdx.x;
  const int lane = tid & 63;
  const int wave = tid >> 6;
  const int ln   = lane & 15;
  const int quad = lane >> 4;
  const int bm = blockIdx.y, bn = blockIdx.x;
  const int m0 = (wave >> 1) * 64;
  const int n0 = (wave & 1) * 64;

  const bf16_t* Abase = A + (size_t)bm * 128 * K;
  const bf16_t* Bbase = Bt + (size_t)bn * 128 * K;

  f32x4 acc[4][4] = {};

  const int kIters = K >> 6;
  for (int kt = 0; kt < kIters; ++kt) {
    __syncthreads();  // previous tile fully consumed
#pragma unroll
    for (int j = 0; j < 4; ++j) {
      const int fb  = j * 256 + wave * 64;   // wave-uniform chunk base
      const int f   = fb + lane;
      const int row = f >> 3, c = f & 7;
      const int gc  = c ^ (row & 7);
      const size_t goff = (size_t)row * K + kt * 64 + gc * 8;
      async16(Abase + goff, (char*)As + fb * 16);
      async16(Bbase + goff, (char*)Bs + fb * 16);
    }
    __syncthreads();  // drains vmcnt (compiler inserts before s_barrier)

#pragma unroll
    for (int ks = 0; ks < 2; ++ks) {
      bf16x8 af[4], bfr[4];
#pragma unroll
      for (int i = 0; i < 4; ++i) {
        int row = m0 + 16 * i + ln;
        int c = (ks * 4 + quad) ^ (row & 7);
        af[i] = *(const bf16x8*)((const char*)As + ((row * 8 + c) << 4));
      }
#pragma unroll
      for (int jj = 0; jj < 4; ++jj) {
        int row = n0 + 16 * jj + ln;
        int c = (ks * 4 + quad) ^ (row & 7);
        bfr[jj] = *(const bf16x8*)((const char*)Bs + ((row * 8 + c) << 4));
      }
#pragma unroll
      for (int i = 0; i < 4; ++i)
#pragma unroll
        for (int jj = 0; jj < 4; ++jj)
          acc[i][jj] = __builtin_amdgcn_mfma_f32_16x16x32_bf16(
              af[i], bfr[jj], acc[i][jj], 0, 0, 0);
    }
  }

  // epilogue: C/D layout col=lane&15, row=quad*4+reg  [measured m89/m91]
#pragma unroll
  for (int i = 0; i < 4; ++i) {
    int rowg = bm * 128 + m0 + 16 * i + quad * 4;
#pragma unroll
    for (int j = 0; j < 4; ++j) {
      int colg = bn * 128 + n0 + 16 * j + ln;
      float bb = bias[colg];
#pragma unroll
      for (int r = 0; r < 4; ++r) {
        float val = acc[i][j][r] + bb;
        if (OUT_BF16)
          ((bf16_t*)out)[(size_t)(rowg + r) * N + colg] = (bf16_t)val;
        else
          ((float*)out)[(size_t)(rowg + r) * N + colg] = val;
      }
    }
  }
}

// ---------------------------------------------------------------------------
// Flash attention, causal. Block = (b, h, 64-row q-tile), 256 threads.
// qkv: [B*T][6144] bf16 (Q | K | V per head). attout: [B*T][2048] bf16.
// ---------------------------------------------------------------------------
__global__ __launch_bounds__(256) void attn_kernel(
    const bf16_t* __restrict__ qkv, bf16_t* __restrict__ attout) {
  const int bx = blockIdx.x;
  const int qt = bx & 15;
  const int h  = (bx >> 4) & 15;
  const int b  = bx >> 8;
  const int tid  = threadIdx.x;
  const int lane = tid & 63;
  const int wave = tid >> 6;
  const int ln   = lane & 15;
  const int quad = lane >> 4;

  __shared__ __align__(16) bf16_t Ks[64][128];
  __shared__ __align__(16) bf16_t Vt[128][64];
  __shared__ __align__(16) bf16_t Ps[4][16][64];

  const int q0 = qt * 64 + wave * 16;

  bf16x8 aq[4];
  {
    const bf16_t* qrow = qkv + (size_t)(b * TT + q0 + ln) * DQKV + h * DH;
#pragma unroll
    for (int kt = 0; kt < 4; ++kt)
      aq[kt] = *(const bf16x8*)(qrow + kt * 32 + quad * 8);
  }

  f32x4 o[8] = {};
  float mrow[4], lrow[4];
#pragma unroll
  for (int r = 0; r < 4; ++r) { mrow[r] = -1e30f; lrow[r] = 0.f; }

  const float scale = 0.08838834764831845f;  // 1/sqrt(128)
  const int nChunks = qt + 1;

  for (int c = 0; c < nChunks; ++c) {
    const int kc = c * 64;
    __syncthreads();
#pragma unroll
    for (int i = 0; i < 4; ++i) {
      int v = tid + i * 256;
      int kk = v >> 4, dv = v & 15;
      const bf16_t* krow = qkv + (size_t)(b * TT + kc + kk) * DQKV + DM + h * DH;
      *(bf16x8*)&Ks[kk][dv * 8] = *(const bf16x8*)(krow + dv * 8);
      bf16x8 vv = *(const bf16x8*)(krow + DM + dv * 8);
#pragma unroll
      for (int e = 0; e < 8; ++e) Vt[dv * 8 + e][kk] = vv[e];
    }
    __syncthreads();

    f32x4 sacc[4];
#pragma unroll
    for (int jt = 0; jt < 4; ++jt) {
      sacc[jt] = (f32x4){0.f, 0.f, 0.f, 0.f};
#pragma unroll
      for (int kt = 0; kt < 4; ++kt) {
        bf16x8 bk = *(const bf16x8*)&Ks[jt * 16 + ln][kt * 32 + quad * 8];
        sacc[jt] =
            __builtin_amdgcn_mfma_f32_16x16x32_bf16(aq[kt], bk, sacc[jt], 0, 0, 0);
      }
    }

    float s[4][4], mc[4];
#pragma unroll
    for (int r = 0; r < 4; ++r) mc[r] = -1e30f;
#pragma unroll
    for (int jt = 0; jt < 4; ++jt) {
      int colg = kc + jt * 16 + ln;
#pragma unroll
      for (int r = 0; r < 4; ++r) {
        int rowg = q0 + quad * 4 + r;
        float sv = sacc[jt][r] * scale;
        sv = (colg <= rowg) ? sv : -1e30f;
        s[jt][r] = sv;
        mc[r] = fmaxf(mc[r], sv);
      }
    }
#pragma unroll
    for (int off = 1; off < 16; off <<= 1)
#pragma unroll
      for (int r = 0; r < 4; ++r)
        mc[r] = fmaxf(mc[r], __shfl_xor(mc[r], off, 64));

    float alpha[4];
#pragma unroll
    for (int r = 0; r < 4; ++r) {
      float mnew = fmaxf(mrow[r], mc[r]);
      alpha[r] = __expf(mrow[r] - mnew);
      mrow[r] = mnew;
    }

    float rs[4] = {0.f, 0.f, 0.f, 0.f};
#pragma unroll
    for (int jt = 0; jt < 4; ++jt)
#pragma unroll
      for (int r = 0; r < 4; ++r) {
        float p = __expf(s[jt][r] - mrow[r]);
        rs[r] += p;
        Ps[wave][quad * 4 + r][jt * 16 + ln] = (bf16_t)p;
      }
#pragma unroll
    for (int off = 1; off < 16; off <<= 1)
#pragma unroll
      for (int r = 0; r < 4; ++r) rs[r] += __shfl_xor(rs[r], off, 64);
#pragma unroll
    for (int r = 0; r < 4; ++r) lrow[r] = lrow[r] * alpha[r] + rs[r];

#pragma unroll
    for (int nt = 0; nt < 8; ++nt)
#pragma unroll
      for (int r = 0; r < 4; ++r) o[nt][r] *= alpha[r];

    __syncthreads();

#pragma unroll
    for (int ks = 0; ks < 2; ++ks) {
      bf16x8 ap = *(const bf16x8*)&Ps[wave][ln][ks * 32 + quad * 8];
#pragma unroll
      for (int nt = 0; nt < 8; ++nt) {
        bf16x8 bv = *(const bf16x8*)&Vt[nt * 16 + ln][ks * 32 + quad * 8];
        o[nt] = __builtin_amdgcn_mfma_f32_16x16x32_bf16(ap, bv, o[nt], 0, 0, 0);
      }
    }
  }

#pragma unroll
  for (int r = 0; r < 4; ++r) {
    float inv = 1.0f / lrow[r];
    int t = q0 + quad * 4 + r;
    bf16_t* orow = attout + (size_t)(b * TT + t) * DM + h * DH;
#pragma unroll
    for (int nt = 0; nt < 8; ++nt) orow[nt * 16 + ln] = (bf16_t)(o[nt][r] * inv);
  }
}

// ---------------------------------------------------------------------------
extern "C" void kernel_launch(void* const* d_in, const int* in_sizes, int n_in,
                              void* d_out, int out_size, void* d_ws,
                              size_t ws_size, hipStream_t stream) {
  const float* x     = (const float*)d_in[0];
  const float* w_qkv = (const float*)d_in[1];
  const float* b_qkv = (const float*)d_in[2];
  const float* w_out = (const float*)d_in[3];
  const float* b_out = (const float*)d_in[4];
  float* out = (float*)d_out;

  // ws layout (bytes):
  //   qkv    bf16 [4096][6144]  @ 0          (50,331,648)
  //   wqkv_t bf16 [6144][2048]  @ 50331648   (25,165,824)
  //   wout_t bf16 [2048][2048]  @ 75497472   ( 8,388,608)
  //   xb / attout bf16 [4096][2048] @ 83886080 (16,777,216)  -- aliased:
  //     xb consumed by gemm1 before attn writes attout (stream-ordered)
  char* ws = (char*)d_ws;
  bf16_t* qkv    = (bf16_t*)(ws);
  bf16_t* wqkv_t = (bf16_t*)(ws + 50331648);
  bf16_t* wout_t = (bf16_t*)(ws + 75497472);
  bf16_t* xb     = (bf16_t*)(ws + 83886080);
  bf16_t* attout = xb;

  dim3 blk(256);
  cast_kernel<<<dim3(4096), blk, 0, stream>>>(x, xb);
  transpose_cast_kernel<<<dim3(96, 32), blk, 0, stream>>>(w_qkv, wqkv_t, 2048, 6144);
  transpose_cast_kernel<<<dim3(32, 32), blk, 0, stream>>>(w_out, wout_t, 2048, 2048);
  gemm_bt_kernel<true>
      <<<dim3(48, 32), blk, 0, stream>>>(xb, wqkv_t, b_qkv, qkv, 4096, 6144, 2048);
  attn_kernel<<<dim3(1024), blk, 0, stream>>>(qkv, attout);
  gemm_bt_kernel<false>
      <<<dim3(16, 32), blk, 0, stream>>>(attout, wout_t, b_out, out, 4096, 2048, 2048);
}

// Round 3
// 410.677 us; speedup vs baseline: 2.3912x; 1.3095x over previous
//
#include <hip/hip_runtime.h>
#include <hip/hip_bf16.h>
#include <math.h>

#define DM    2048
#define DQKV  6144
#define NH    16
#define DH    128
#define TT    1024
#define BB    4

typedef __bf16 bf16_t;
typedef __bf16 bf16x4 __attribute__((ext_vector_type(4)));
typedef __bf16 bf16x8 __attribute__((ext_vector_type(8)));
typedef float  f32x4  __attribute__((ext_vector_type(4)));

__device__ __forceinline__ void async16(const void* g, void* lds) {
  __builtin_amdgcn_global_load_lds(
      (const __attribute__((address_space(1))) unsigned int*)g,
      (__attribute__((address_space(3))) unsigned int*)lds, 16, 0, 0);
}

// ---------------------------------------------------------------------------
// cast fp32 -> bf16, 8 elems/thread
// ---------------------------------------------------------------------------
__global__ __launch_bounds__(256) void cast_kernel(const float* __restrict__ X,
                                                   bf16_t* __restrict__ Xb) {
  const size_t i = ((size_t)blockIdx.x * 256 + threadIdx.x) * 8;
  float4 a = *(const float4*)(X + i);
  float4 b = *(const float4*)(X + i + 4);
  bf16x8 o = {(bf16_t)a.x, (bf16_t)a.y, (bf16_t)a.z, (bf16_t)a.w,
              (bf16_t)b.x, (bf16_t)b.y, (bf16_t)b.z, (bf16_t)b.w};
  *(bf16x8*)(Xb + i) = o;
}

// ---------------------------------------------------------------------------
// W[K][N] fp32 -> Wt[N][K] bf16, 64x64 tiles
// ---------------------------------------------------------------------------
__global__ __launch_bounds__(256) void transpose_cast_kernel(
    const float* __restrict__ W, bf16_t* __restrict__ Wt, int K, int N) {
  __shared__ bf16_t tile[64][72];
  const int tid = threadIdx.x;
  const int tk = blockIdx.y * 64, tn = blockIdx.x * 64;
  {
    int r = tid >> 2, c0 = (tid & 3) * 16;
    const float* src = W + (size_t)(tk + r) * N + tn + c0;
#pragma unroll
    for (int j = 0; j < 4; ++j) {
      float4 v = *(const float4*)(src + j * 4);
      tile[r][c0 + j * 4 + 0] = (bf16_t)v.x;
      tile[r][c0 + j * 4 + 1] = (bf16_t)v.y;
      tile[r][c0 + j * 4 + 2] = (bf16_t)v.z;
      tile[r][c0 + j * 4 + 3] = (bf16_t)v.w;
    }
  }
  __syncthreads();
  {
    int n = tid >> 2, c0 = (tid & 3) * 16;
    bf16_t* dst = Wt + (size_t)(tn + n) * K + tk + c0;
#pragma unroll
    for (int j = 0; j < 4; ++j) {
      bf16x4 t = {tile[c0 + j * 4 + 0][n], tile[c0 + j * 4 + 1][n],
                  tile[c0 + j * 4 + 2][n], tile[c0 + j * 4 + 3][n]};
      *(bf16x4*)(dst + j * 4) = t;
    }
  }
}

// ---------------------------------------------------------------------------
// GEMM: C[M,N] = A[M,K] @ Bt[N,K]^T + bias[N].  All bf16 inputs, fp32 acc.
// (unchanged from R2: m97 structure, BK=64, async16 staging, XOR swizzle)
// ---------------------------------------------------------------------------
template <bool OUT_BF16>
__global__ __launch_bounds__(256) void gemm_bt_kernel(
    const bf16_t* __restrict__ A, const bf16_t* __restrict__ Bt,
    const float* __restrict__ bias, void* __restrict__ out,
    int M, int N, int K) {
  __shared__ __align__(16) bf16_t As[128 * 64];
  __shared__ __align__(16) bf16_t Bs[128 * 64];

  const int tid  = threadIdx.x;
  const int lane = tid & 63;
  const int wave = tid >> 6;
  const int ln   = lane & 15;
  const int quad = lane >> 4;
  const int bm = blockIdx.y, bn = blockIdx.x;
  const int m0 = (wave >> 1) * 64;
  const int n0 = (wave & 1) * 64;

  const bf16_t* Abase = A + (size_t)bm * 128 * K;
  const bf16_t* Bbase = Bt + (size_t)bn * 128 * K;

  f32x4 acc[4][4] = {};

  const int kIters = K >> 6;
  for (int kt = 0; kt < kIters; ++kt) {
    __syncthreads();
#pragma unroll
    for (int j = 0; j < 4; ++j) {
      const int fb  = j * 256 + wave * 64;
      const int f   = fb + lane;
      const int row = f >> 3, c = f & 7;
      const int gc  = c ^ (row & 7);
      const size_t goff = (size_t)row * K + kt * 64 + gc * 8;
      async16(Abase + goff, (char*)As + fb * 16);
      async16(Bbase + goff, (char*)Bs + fb * 16);
    }
    __syncthreads();

#pragma unroll
    for (int ks = 0; ks < 2; ++ks) {
      bf16x8 af[4], bfr[4];
#pragma unroll
      for (int i = 0; i < 4; ++i) {
        int row = m0 + 16 * i + ln;
        int c = (ks * 4 + quad) ^ (row & 7);
        af[i] = *(const bf16x8*)((const char*)As + ((row * 8 + c) << 4));
      }
#pragma unroll
      for (int jj = 0; jj < 4; ++jj) {
        int row = n0 + 16 * jj + ln;
        int c = (ks * 4 + quad) ^ (row & 7);
        bfr[jj] = *(const bf16x8*)((const char*)Bs + ((row * 8 + c) << 4));
      }
#pragma unroll
      for (int i = 0; i < 4; ++i)
#pragma unroll
        for (int jj = 0; jj < 4; ++jj)
          acc[i][jj] = __builtin_amdgcn_mfma_f32_16x16x32_bf16(
              af[i], bfr[jj], acc[i][jj], 0, 0, 0);
    }
  }

#pragma unroll
  for (int i = 0; i < 4; ++i) {
    int rowg = bm * 128 + m0 + 16 * i + quad * 4;
#pragma unroll
    for (int j = 0; j < 4; ++j) {
      int colg = bn * 128 + n0 + 16 * j + ln;
      float bb = bias[colg];
#pragma unroll
      for (int r = 0; r < 4; ++r) {
        float val = acc[i][j][r] + bb;
        if (OUT_BF16)
          ((bf16_t*)out)[(size_t)(rowg + r) * N + colg] = (bf16_t)val;
        else
          ((float*)out)[(size_t)(rowg + r) * N + colg] = val;
      }
    }
  }
}

// ---------------------------------------------------------------------------
// Flash attention, causal. 512 blocks: (b, h, pair p). Block handles q-tiles
// p and 15-p -> exactly 17 K-chunks per block (perfect static balance).
// All LDS surfaces XOR-chunk-swizzled (chunk c stored at c^(row&7)): Ks via
// global_load_lds DMA; Vt scatter-staged with kk=lane so writes spread over
// all 32 banks (2-way = free, m136); Ps per-wave round-trip swizzled.
// ---------------------------------------------------------------------------
__global__ __launch_bounds__(256) void attn_kernel(
    const bf16_t* __restrict__ qkv, bf16_t* __restrict__ attout) {
  const int bx = blockIdx.x;
  const int p  = bx & 7;
  const int h  = (bx >> 3) & 15;
  const int b  = bx >> 7;
  const int tid  = threadIdx.x;
  const int lane = tid & 63;
  const int wave = tid >> 6;
  const int ln   = lane & 15;
  const int quad = lane >> 4;

  __shared__ __align__(16) bf16_t Ks[64 * 128];   // [kk][d] swizzled, 16 KB
  __shared__ __align__(16) bf16_t Vt[128 * 64];   // [d][kk] swizzled, 16 KB
  __shared__ __align__(16) bf16_t Ps[4 * 16 * 64];// per-wave P, swizzled, 8 KB

  const float scale = 0.08838834764831845f;  // 1/sqrt(128)

  for (int half = 0; half < 2; ++half) {
    const int qt = half ? (15 - p) : p;
    const int q0 = qt * 64 + wave * 16;

    // Q fragments: A-layout m=ln, k=quad*8+j
    bf16x8 aq[4];
    {
      const bf16_t* qrow = qkv + (size_t)(b * TT + q0 + ln) * DQKV + h * DH;
#pragma unroll
      for (int kt = 0; kt < 4; ++kt)
        aq[kt] = *(const bf16x8*)(qrow + kt * 32 + quad * 8);
    }

    f32x4 o[8] = {};
    float mrow[4], lrow[4];
#pragma unroll
    for (int r = 0; r < 4; ++r) { mrow[r] = -1e30f; lrow[r] = 0.f; }

    for (int c = 0; c <= qt; ++c) {
      const int kc = c * 64;
      __syncthreads();  // previous chunk fully consumed

      // --- stage K via DMA: 1024 16B chunks, LDS chunk (row,cc) = global cc^(row&7)
#pragma unroll
      for (int j = 0; j < 4; ++j) {
        const int fb  = j * 256 + wave * 64;  // wave-uniform
        const int l   = fb + lane;
        const int row = l >> 4, cc = l & 15;
        const int gc  = cc ^ (row & 7);
        const bf16_t* g =
            qkv + (size_t)(b * TT + kc + row) * DQKV + DM + h * DH + gc * 8;
        async16(g, (char*)Ks + fb * 16);
      }
      // --- stage V transposed: kk = lane spreads banks; write el (d, kk) at
      //     chunk (kk>>3)^(d&7)
#pragma unroll
      for (int i = 0; i < 4; ++i) {
        const int v  = tid + i * 256;
        const int kk = v & 63;
        const int dg = v >> 6;  // wave-uniform per iter
        bf16x8 vv = *(const bf16x8*)(
            qkv + (size_t)(b * TT + kc + kk) * DQKV + 2 * DM + h * DH + dg * 8);
#pragma unroll
        for (int e = 0; e < 8; ++e) {
          const int d  = dg * 8 + e;
          const int sc = (kk >> 3) ^ (d & 7);
          Vt[d * 64 + sc * 8 + (kk & 7)] = vv[e];
        }
      }
      __syncthreads();  // drains vmcnt+lgkmcnt

      // --- S = Q K^T
      f32x4 sacc[4];
#pragma unroll
      for (int jt = 0; jt < 4; ++jt) {
        sacc[jt] = (f32x4){0.f, 0.f, 0.f, 0.f};
#pragma unroll
        for (int kt = 0; kt < 4; ++kt) {
          const int row = jt * 16 + ln;
          const int sc  = (kt * 4 + quad) ^ (row & 7);
          bf16x8 bk = *(const bf16x8*)((const char*)Ks + row * 256 + sc * 16);
          sacc[jt] = __builtin_amdgcn_mfma_f32_16x16x32_bf16(aq[kt], bk,
                                                             sacc[jt], 0, 0, 0);
        }
      }

      // --- softmax update (rows in quad*4+r, cols in ln)
      float s[4][4], mc[4];
#pragma unroll
      for (int r = 0; r < 4; ++r) mc[r] = -1e30f;
      const bool diag = (c == qt);
#pragma unroll
      for (int jt = 0; jt < 4; ++jt) {
        int colg = kc + jt * 16 + ln;
#pragma unroll
        for (int r = 0; r < 4; ++r) {
          float sv = sacc[jt][r] * scale;
          if (diag) {
            int rowg = q0 + quad * 4 + r;
            sv = (colg <= rowg) ? sv : -1e30f;
          }
          s[jt][r] = sv;
          mc[r] = fmaxf(mc[r], sv);
        }
      }
#pragma unroll
      for (int off = 1; off < 16; off <<= 1)
#pragma unroll
        for (int r = 0; r < 4; ++r)
          mc[r] = fmaxf(mc[r], __shfl_xor(mc[r], off, 64));

      float alpha[4];
#pragma unroll
      for (int r = 0; r < 4; ++r) {
        float mnew = fmaxf(mrow[r], mc[r]);
        alpha[r] = __expf(mrow[r] - mnew);
        mrow[r] = mnew;
      }

      float rs[4] = {0.f, 0.f, 0.f, 0.f};
#pragma unroll
      for (int jt = 0; jt < 4; ++jt)
#pragma unroll
        for (int r = 0; r < 4; ++r) {
          float pv = __expf(s[jt][r] - mrow[r]);
          rs[r] += pv;
          const int row = quad * 4 + r;
          const int col = jt * 16 + ln;
          const int sc  = (col >> 3) ^ (row & 7);
          Ps[wave * 1024 + row * 64 + sc * 8 + (col & 7)] = (bf16_t)pv;
        }
#pragma unroll
      for (int off = 1; off < 16; off <<= 1)
#pragma unroll
        for (int r = 0; r < 4; ++r) rs[r] += __shfl_xor(rs[r], off, 64);
#pragma unroll
      for (int r = 0; r < 4; ++r) lrow[r] = lrow[r] * alpha[r] + rs[r];

#pragma unroll
      for (int nt = 0; nt < 8; ++nt)
#pragma unroll
        for (int r = 0; r < 4; ++r) o[nt][r] *= alpha[r];

      // --- O += P V  (Ps is per-wave; DS pipe is in-order per wave -> no barrier)
#pragma unroll
      for (int ks = 0; ks < 2; ++ks) {
        const int psc = (ks * 4 + quad) ^ (ln & 7);
        bf16x8 ap =
            *(const bf16x8*)((const char*)Ps + wave * 2048 + ln * 128 + psc * 16);
#pragma unroll
        for (int nt = 0; nt < 8; ++nt) {
          const int row = nt * 16 + ln;
          const int sc  = (ks * 4 + quad) ^ (row & 7);
          bf16x8 bv = *(const bf16x8*)((const char*)Vt + row * 128 + sc * 16);
          o[nt] = __builtin_amdgcn_mfma_f32_16x16x32_bf16(ap, bv, o[nt], 0, 0, 0);
        }
      }
    }

    // epilogue: normalize, write bf16
#pragma unroll
    for (int r = 0; r < 4; ++r) {
      float inv = 1.0f / lrow[r];
      int t = q0 + quad * 4 + r;
      bf16_t* orow = attout + (size_t)(b * TT + t) * DM + h * DH;
#pragma unroll
      for (int nt = 0; nt < 8; ++nt)
        orow[nt * 16 + ln] = (bf16_t)(o[nt][r] * inv);
    }
  }
}

// ---------------------------------------------------------------------------
extern "C" void kernel_launch(void* const* d_in, const int* in_sizes, int n_in,
                              void* d_out, int out_size, void* d_ws,
                              size_t ws_size, hipStream_t stream) {
  const float* x     = (const float*)d_in[0];
  const float* w_qkv = (const float*)d_in[1];
  const float* b_qkv = (const float*)d_in[2];
  const float* w_out = (const float*)d_in[3];
  const float* b_out = (const float*)d_in[4];
  float* out = (float*)d_out;

  char* ws = (char*)d_ws;
  bf16_t* qkv    = (bf16_t*)(ws);
  bf16_t* wqkv_t = (bf16_t*)(ws + 50331648);
  bf16_t* wout_t = (bf16_t*)(ws + 75497472);
  bf16_t* xb     = (bf16_t*)(ws + 83886080);
  bf16_t* attout = xb;  // aliased: xb consumed by gemm1 before attn writes

  dim3 blk(256);
  cast_kernel<<<dim3(4096), blk, 0, stream>>>(x, xb);
  transpose_cast_kernel<<<dim3(96, 32), blk, 0, stream>>>(w_qkv, wqkv_t, 2048, 6144);
  transpose_cast_kernel<<<dim3(32, 32), blk, 0, stream>>>(w_out, wout_t, 2048, 2048);
  gemm_bt_kernel<true>
      <<<dim3(48, 32), blk, 0, stream>>>(xb, wqkv_t, b_qkv, qkv, 4096, 6144, 2048);
  attn_kernel<<<dim3(512), blk, 0, stream>>>(qkv, attout);
  gemm_bt_kernel<false>
      <<<dim3(16, 32), blk, 0, stream>>>(attout, wout_t, b_out, out, 4096, 2048, 2048);
}

// Round 4
// 369.343 us; speedup vs baseline: 2.6588x; 1.1119x over previous
//
#include <hip/hip_runtime.h>
#include <hip/hip_bf16.h>
#include <math.h>

#define DM    2048
#define DQKV  6144
#define NH    16
#define DH    128
#define TT    1024
#define BB    4

typedef __bf16 bf16_t;
typedef __bf16 bf16x4 __attribute__((ext_vector_type(4)));
typedef __bf16 bf16x8 __attribute__((ext_vector_type(8)));
typedef float  f32x4  __attribute__((ext_vector_type(4)));

__device__ __forceinline__ void async16(const void* g, void* lds) {
  __builtin_amdgcn_global_load_lds(
      (const __attribute__((address_space(1))) unsigned int*)g,
      (__attribute__((address_space(3))) unsigned int*)lds, 16, 0, 0);
}

// ---------------------------------------------------------------------------
// cast fp32 -> bf16, 8 elems/thread
// ---------------------------------------------------------------------------
__global__ __launch_bounds__(256) void cast_kernel(const float* __restrict__ X,
                                                   bf16_t* __restrict__ Xb) {
  const size_t i = ((size_t)blockIdx.x * 256 + threadIdx.x) * 8;
  float4 a = *(const float4*)(X + i);
  float4 b = *(const float4*)(X + i + 4);
  bf16x8 o = {(bf16_t)a.x, (bf16_t)a.y, (bf16_t)a.z, (bf16_t)a.w,
              (bf16_t)b.x, (bf16_t)b.y, (bf16_t)b.z, (bf16_t)b.w};
  *(bf16x8*)(Xb + i) = o;
}

// ---------------------------------------------------------------------------
// W[K][N] fp32 -> Wt[N][K] bf16, 64x64 tiles
// ---------------------------------------------------------------------------
__global__ __launch_bounds__(256) void transpose_cast_kernel(
    const float* __restrict__ W, bf16_t* __restrict__ Wt, int K, int N) {
  __shared__ bf16_t tile[64][72];
  const int tid = threadIdx.x;
  const int tk = blockIdx.y * 64, tn = blockIdx.x * 64;
  {
    int r = tid >> 2, c0 = (tid & 3) * 16;
    const float* src = W + (size_t)(tk + r) * N + tn + c0;
#pragma unroll
    for (int j = 0; j < 4; ++j) {
      float4 v = *(const float4*)(src + j * 4);
      tile[r][c0 + j * 4 + 0] = (bf16_t)v.x;
      tile[r][c0 + j * 4 + 1] = (bf16_t)v.y;
      tile[r][c0 + j * 4 + 2] = (bf16_t)v.z;
      tile[r][c0 + j * 4 + 3] = (bf16_t)v.w;
    }
  }
  __syncthreads();
  {
    int n = tid >> 2, c0 = (tid & 3) * 16;
    bf16_t* dst = Wt + (size_t)(tn + n) * K + tk + c0;
#pragma unroll
    for (int j = 0; j < 4; ++j) {
      bf16x4 t = {tile[c0 + j * 4 + 0][n], tile[c0 + j * 4 + 1][n],
                  tile[c0 + j * 4 + 2][n], tile[c0 + j * 4 + 3][n]};
      *(bf16x4*)(dst + j * 4) = t;
    }
  }
}

// ---------------------------------------------------------------------------
// V transpose: qkv V-part [B*T][h*128+d] -> Vt_g[(b*NH+h)*DH + d][T] bf16.
// 64(t) x 64(d) tiles through LDS; both global sides coalesced.
// ---------------------------------------------------------------------------
__global__ __launch_bounds__(256) void v_transpose_kernel(
    const bf16_t* __restrict__ qkv, bf16_t* __restrict__ Vt_g) {
  __shared__ bf16_t tile[64][72];
  const int tid = threadIdx.x;
  const int dt = blockIdx.x;       // 0..1  (d-tile)
  const int tt = blockIdx.y;       // 0..15 (t-tile)
  const int bh = blockIdx.z;       // 0..63
  const int b = bh >> 4, h = bh & 15;
  {
    int r = tid >> 2, c0 = (tid & 3) * 16;
    const bf16_t* src =
        qkv + (size_t)(b * TT + tt * 64 + r) * DQKV + 2 * DM + h * DH + dt * 64 + c0;
    *(bf16x8*)&tile[r][c0]     = *(const bf16x8*)(src);
    *(bf16x8*)&tile[r][c0 + 8] = *(const bf16x8*)(src + 8);
  }
  __syncthreads();
  {
    int n = tid >> 2, c0 = (tid & 3) * 16;
    bf16_t* dst = Vt_g + (size_t)(bh * DH + dt * 64 + n) * TT + tt * 64 + c0;
#pragma unroll
    for (int j = 0; j < 4; ++j) {
      bf16x4 t = {tile[c0 + j * 4 + 0][n], tile[c0 + j * 4 + 1][n],
                  tile[c0 + j * 4 + 2][n], tile[c0 + j * 4 + 3][n]};
      *(bf16x4*)(dst + j * 4) = t;
    }
  }
}

// ---------------------------------------------------------------------------
// GEMM: C[M,N] = A[M,K] @ Bt[N,K]^T + bias[N].  (unchanged m97 structure)
// ---------------------------------------------------------------------------
template <bool OUT_BF16>
__global__ __launch_bounds__(256) void gemm_bt_kernel(
    const bf16_t* __restrict__ A, const bf16_t* __restrict__ Bt,
    const float* __restrict__ bias, void* __restrict__ out,
    int M, int N, int K) {
  __shared__ __align__(16) bf16_t As[128 * 64];
  __shared__ __align__(16) bf16_t Bs[128 * 64];

  const int tid  = threadIdx.x;
  const int lane = tid & 63;
  const int wave = tid >> 6;
  const int ln   = lane & 15;
  const int quad = lane >> 4;
  const int bm = blockIdx.y, bn = blockIdx.x;
  const int m0 = (wave >> 1) * 64;
  const int n0 = (wave & 1) * 64;

  const bf16_t* Abase = A + (size_t)bm * 128 * K;
  const bf16_t* Bbase = Bt + (size_t)bn * 128 * K;

  f32x4 acc[4][4] = {};

  const int kIters = K >> 6;
  for (int kt = 0; kt < kIters; ++kt) {
    __syncthreads();
#pragma unroll
    for (int j = 0; j < 4; ++j) {
      const int fb  = j * 256 + wave * 64;
      const int f   = fb + lane;
      const int row = f >> 3, c = f & 7;
      const int gc  = c ^ (row & 7);
      const size_t goff = (size_t)row * K + kt * 64 + gc * 8;
      async16(Abase + goff, (char*)As + fb * 16);
      async16(Bbase + goff, (char*)Bs + fb * 16);
    }
    __syncthreads();

#pragma unroll
    for (int ks = 0; ks < 2; ++ks) {
      bf16x8 af[4], bfr[4];
#pragma unroll
      for (int i = 0; i < 4; ++i) {
        int row = m0 + 16 * i + ln;
        int c = (ks * 4 + quad) ^ (row & 7);
        af[i] = *(const bf16x8*)((const char*)As + ((row * 8 + c) << 4));
      }
#pragma unroll
      for (int jj = 0; jj < 4; ++jj) {
        int row = n0 + 16 * jj + ln;
        int c = (ks * 4 + quad) ^ (row & 7);
        bfr[jj] = *(const bf16x8*)((const char*)Bs + ((row * 8 + c) << 4));
      }
#pragma unroll
      for (int i = 0; i < 4; ++i)
#pragma unroll
        for (int jj = 0; jj < 4; ++jj)
          acc[i][jj] = __builtin_amdgcn_mfma_f32_16x16x32_bf16(
              af[i], bfr[jj], acc[i][jj], 0, 0, 0);
    }
  }

#pragma unroll
  for (int i = 0; i < 4; ++i) {
    int rowg = bm * 128 + m0 + 16 * i + quad * 4;
#pragma unroll
    for (int j = 0; j < 4; ++j) {
      int colg = bn * 128 + n0 + 16 * j + ln;
      float bb = bias[colg];
#pragma unroll
      for (int r = 0; r < 4; ++r) {
        float val = acc[i][j][r] + bb;
        if (OUT_BF16)
          ((bf16_t*)out)[(size_t)(rowg + r) * N + colg] = (bf16_t)val;
        else
          ((float*)out)[(size_t)(rowg + r) * N + colg] = val;
      }
    }
  }
}

// ---------------------------------------------------------------------------
// Flash attention, causal. 512 blocks: (b, h, pair p) -> q-tiles p and 15-p
// (17 chunks/block, perfect balance). K and V both staged via global_load_lds
// DMA (V from pre-transposed Vt_g), XOR-chunk-swizzled. Double-buffered with
// a single barrier per chunk: prefetch c+1 issued after the iter-c barrier,
// overlapping the DMA with chunk-c compute. K/V depend only on chunk index,
// so the half-1 chunk-0 prefetch overlaps half-0's last compute + epilogue.
// ---------------------------------------------------------------------------
__global__ __launch_bounds__(256) void attn_kernel(
    const bf16_t* __restrict__ qkv, const bf16_t* __restrict__ Vt_g,
    bf16_t* __restrict__ attout) {
  const int bx = blockIdx.x;
  const int p  = bx & 7;
  const int h  = (bx >> 3) & 15;
  const int b  = bx >> 7;
  const int bh = b * NH + h;
  const int tid  = threadIdx.x;
  const int lane = tid & 63;
  const int wave = tid >> 6;
  const int ln   = lane & 15;
  const int quad = lane >> 4;

  __shared__ __align__(16) bf16_t Ks[2][64 * 128];   // 2x16 KB, swizzled
  __shared__ __align__(16) bf16_t Vs[2][128 * 64];   // 2x16 KB, [d][kk] swizzled
  __shared__ __align__(16) bf16_t Ps[4 * 16 * 64];   // 8 KB per-wave P

  const float scale = 0.08838834764831845f;  // 1/sqrt(128)

  // prefetch chunk c's K (row-major) and V (d-major) into buffer bufi
  auto prefetch = [&](int c, int bufi) {
    const int kc = c * 64;
#pragma unroll
    for (int j = 0; j < 4; ++j) {
      const int fb = j * 256 + wave * 64;  // wave-uniform chunk base
      const int l  = fb + lane;
      {  // K: 64 rows x 16 chunks, LDS chunk (row,cc) = global cc^(row&7)
        const int row = l >> 4, cc = l & 15;
        const int gc  = cc ^ (row & 7);
        const bf16_t* g =
            qkv + (size_t)(b * TT + kc + row) * DQKV + DM + h * DH + gc * 8;
        async16(g, (char*)Ks[bufi] + fb * 16);
      }
      {  // V: 128 rows(d) x 8 chunks(kk), LDS chunk (d,cc) = global cc^(d&7)
        const int d = l >> 3, cc = l & 7;
        const int gc = cc ^ (d & 7);
        const bf16_t* g = Vt_g + (size_t)(bh * DH + d) * TT + kc + gc * 8;
        async16(g, (char*)Vs[bufi] + fb * 16);
      }
    }
  };

  int buf = 0;
  prefetch(0, 0);

  for (int half = 0; half < 2; ++half) {
    const int qt = half ? (15 - p) : p;
    const int q0 = qt * 64 + wave * 16;

    // Q fragments: A-layout m=ln, k=quad*8+j
    bf16x8 aq[4];
    {
      const bf16_t* qrow = qkv + (size_t)(b * TT + q0 + ln) * DQKV + h * DH;
#pragma unroll
      for (int kt = 0; kt < 4; ++kt)
        aq[kt] = *(const bf16x8*)(qrow + kt * 32 + quad * 8);
    }

    f32x4 o[8] = {};
    float mrow[4], lrow[4];
#pragma unroll
    for (int r = 0; r < 4; ++r) { mrow[r] = -1e30f; lrow[r] = 0.f; }

    for (int c = 0; c <= qt; ++c) {
      const int kc = c * 64;
      __syncthreads();  // drains prefetch of chunk c; all waves done w/ buf^1

      if (c < qt)                prefetch(c + 1, buf ^ 1);
      else if (half == 0)        prefetch(0,     buf ^ 1);  // next half reuses c=0

      const bf16_t* KsB = Ks[buf];
      const bf16_t* VsB = Vs[buf];

      // --- S = Q K^T
      f32x4 sacc[4];
#pragma unroll
      for (int jt = 0; jt < 4; ++jt) {
        sacc[jt] = (f32x4){0.f, 0.f, 0.f, 0.f};
#pragma unroll
        for (int kt = 0; kt < 4; ++kt) {
          const int row = jt * 16 + ln;
          const int sc  = (kt * 4 + quad) ^ (row & 7);
          bf16x8 bk = *(const bf16x8*)((const char*)KsB + row * 256 + sc * 16);
          sacc[jt] = __builtin_amdgcn_mfma_f32_16x16x32_bf16(aq[kt], bk,
                                                             sacc[jt], 0, 0, 0);
        }
      }

      // --- softmax update (rows in quad*4+r, cols in ln)
      float s[4][4], mc[4];
#pragma unroll
      for (int r = 0; r < 4; ++r) mc[r] = -1e30f;
      const bool diag = (c == qt);
#pragma unroll
      for (int jt = 0; jt < 4; ++jt) {
        int colg = kc + jt * 16 + ln;
#pragma unroll
        for (int r = 0; r < 4; ++r) {
          float sv = sacc[jt][r] * scale;
          if (diag) {
            int rowg = q0 + quad * 4 + r;
            sv = (colg <= rowg) ? sv : -1e30f;
          }
          s[jt][r] = sv;
          mc[r] = fmaxf(mc[r], sv);
        }
      }
#pragma unroll
      for (int off = 1; off < 16; off <<= 1)
#pragma unroll
        for (int r = 0; r < 4; ++r)
          mc[r] = fmaxf(mc[r], __shfl_xor(mc[r], off, 64));

      float alpha[4];
#pragma unroll
      for (int r = 0; r < 4; ++r) {
        float mnew = fmaxf(mrow[r], mc[r]);
        alpha[r] = __expf(mrow[r] - mnew);
        mrow[r] = mnew;
      }

      float rs[4] = {0.f, 0.f, 0.f, 0.f};
#pragma unroll
      for (int jt = 0; jt < 4; ++jt)
#pragma unroll
        for (int r = 0; r < 4; ++r) {
          float pv = __expf(s[jt][r] - mrow[r]);
          rs[r] += pv;
          const int row = quad * 4 + r;
          const int col = jt * 16 + ln;
          const int sc  = (col >> 3) ^ (row & 7);
          Ps[wave * 1024 + row * 64 + sc * 8 + (col & 7)] = (bf16_t)pv;
        }
#pragma unroll
      for (int off = 1; off < 16; off <<= 1)
#pragma unroll
        for (int r = 0; r < 4; ++r) rs[r] += __shfl_xor(rs[r], off, 64);
#pragma unroll
      for (int r = 0; r < 4; ++r) lrow[r] = lrow[r] * alpha[r] + rs[r];

#pragma unroll
      for (int nt = 0; nt < 8; ++nt)
#pragma unroll
        for (int r = 0; r < 4; ++r) o[nt][r] *= alpha[r];

      // --- O += P V  (Ps per-wave; DS pipe in-order per wave -> no barrier)
#pragma unroll
      for (int ks = 0; ks < 2; ++ks) {
        const int psc = (ks * 4 + quad) ^ (ln & 7);
        bf16x8 ap =
            *(const bf16x8*)((const char*)Ps + wave * 2048 + ln * 128 + psc * 16);
#pragma unroll
        for (int nt = 0; nt < 8; ++nt) {
          const int row = nt * 16 + ln;
          const int sc  = (ks * 4 + quad) ^ (row & 7);
          bf16x8 bv = *(const bf16x8*)((const char*)VsB + row * 128 + sc * 16);
          o[nt] = __builtin_amdgcn_mfma_f32_16x16x32_bf16(ap, bv, o[nt], 0, 0, 0);
        }
      }
      buf ^= 1;
    }

    // epilogue: normalize, write bf16
#pragma unroll
    for (int r = 0; r < 4; ++r) {
      float inv = 1.0f / lrow[r];
      int t = q0 + quad * 4 + r;
      bf16_t* orow = attout + (size_t)(b * TT + t) * DM + h * DH;
#pragma unroll
      for (int nt = 0; nt < 8; ++nt)
        orow[nt * 16 + ln] = (bf16_t)(o[nt][r] * inv);
    }
  }
}

// ---------------------------------------------------------------------------
extern "C" void kernel_launch(void* const* d_in, const int* in_sizes, int n_in,
                              void* d_out, int out_size, void* d_ws,
                              size_t ws_size, hipStream_t stream) {
  const float* x     = (const float*)d_in[0];
  const float* w_qkv = (const float*)d_in[1];
  const float* b_qkv = (const float*)d_in[2];
  const float* w_out = (const float*)d_in[3];
  const float* b_out = (const float*)d_in[4];
  float* out = (float*)d_out;

  // ws layout (bytes):
  //   qkv    bf16 [4096][6144]  @ 0          (50,331,648)
  //   wqkv_t bf16 [6144][2048]  @ 50331648   (25,165,824)  -- after gemm1 this
  //          region is dead; Vt_g bf16 [64][128][1024] (16.8 MB) aliases it.
  //   wout_t bf16 [2048][2048]  @ 75497472   ( 8,388,608)
  //   xb / attout bf16 [4096][2048] @ 83886080 (16,777,216) -- aliased
  char* ws = (char*)d_ws;
  bf16_t* qkv    = (bf16_t*)(ws);
  bf16_t* wqkv_t = (bf16_t*)(ws + 50331648);
  bf16_t* Vt_g   = wqkv_t;  // alias: wqkv_t consumed by gemm1 before v_transpose
  bf16_t* wout_t = (bf16_t*)(ws + 75497472);
  bf16_t* xb     = (bf16_t*)(ws + 83886080);
  bf16_t* attout = xb;      // alias: xb consumed by gemm1 before attn writes

  dim3 blk(256);
  cast_kernel<<<dim3(4096), blk, 0, stream>>>(x, xb);
  transpose_cast_kernel<<<dim3(96, 32), blk, 0, stream>>>(w_qkv, wqkv_t, 2048, 6144);
  transpose_cast_kernel<<<dim3(32, 32), blk, 0, stream>>>(w_out, wout_t, 2048, 2048);
  gemm_bt_kernel<true>
      <<<dim3(48, 32), blk, 0, stream>>>(xb, wqkv_t, b_qkv, qkv, 4096, 6144, 2048);
  v_transpose_kernel<<<dim3(2, 16, 64), blk, 0, stream>>>(qkv, Vt_g);
  attn_kernel<<<dim3(512), blk, 0, stream>>>(qkv, Vt_g, attout);
  gemm_bt_kernel<false>
      <<<dim3(16, 32), blk, 0, stream>>>(attout, wout_t, b_out, out, 4096, 2048, 2048);
}